// Round 1
// baseline (307.626 us; speedup 1.0000x reference)
//
#include <hip/hip_runtime.h>
#include <hip/hip_bf16.h>
#include <stdint.h>

#define KC   8      // mixture components
#define DIM  512    // obs dim
#define HID  512    // hidden
#define ACTN 1024   // actions
#define NS   64     // sequences
#define NT   128    // timesteps
#define NB   8192   // NS*NT

typedef __attribute__((ext_vector_type(8))) short short8;
typedef __attribute__((ext_vector_type(8))) unsigned short ushort8;
typedef __attribute__((ext_vector_type(4))) float floatx4;
typedef __attribute__((ext_vector_type(4))) unsigned int uint4v;

__device__ inline float bf2f(unsigned short u) {
    return __uint_as_float(((unsigned int)u) << 16);
}
__device__ inline unsigned short f2bf(float x) {
    return __builtin_bit_cast(unsigned short, __float2bfloat16(x));
}

// ---------------- fp32 -> bf16 flat convert (obs) ----------------
__global__ __launch_bounds__(256) void convert_bf16_kernel(
    const float* __restrict__ in, unsigned short* __restrict__ out, int n8)
{
    int i = blockIdx.x * 256 + threadIdx.x;
    if (i >= n8) return;
    const float* p = in + (size_t)i * 8;
    ushort8 u;
#pragma unroll
    for (int j = 0; j < 8; j++) u[j] = f2bf(p[j]);
    *(ushort8*)(out + (size_t)i * 8) = u;
}

// ---------------- fp32 [z][R][C] -> bf16 [z][C][R] transpose ----------------
__global__ __launch_bounds__(256) void transpose_bf16_kernel(
    const float* __restrict__ in, unsigned short* __restrict__ out, int R, int C)
{
    __shared__ float tile[32][33];
    int z = blockIdx.z;
    const float* src = in + (size_t)z * R * C;
    unsigned short* dst = out + (size_t)z * R * C;
    int c = blockIdx.x * 32 + threadIdx.x;
    int r0 = blockIdx.y * 32;
#pragma unroll
    for (int i = 0; i < 32; i += 8)
        tile[threadIdx.y + i][threadIdx.x] = src[(size_t)(r0 + threadIdx.y + i) * C + c];
    __syncthreads();
    int outr = blockIdx.x * 32 + threadIdx.y;   // new row = old col
    int outc = r0 + threadIdx.x;                // new col = old row
#pragma unroll
    for (int i = 0; i < 32; i += 8)
        dst[(size_t)(outr + i) * R + outc] = f2bf(tile[threadIdx.x][threadIdx.y + i]);
}

// ---------------- batched bf16 MFMA GEMM: C[z] = A[z] * Bt[z]^T + bias ----------------
// A: [M][Kd] bf16 row-major, Bt: [N][Kd] bf16 row-major (i.e. B transposed),
// bias fp32 [N], C: [M][N] bf16. Optional ReLU.
__global__ __launch_bounds__(256, 2) void gemm_bt_kernel(
    const unsigned short* __restrict__ Aall,
    const unsigned short* __restrict__ Btall,
    const float* __restrict__ biasall,
    unsigned short* __restrict__ Call,
    int M, int N, int Kd,
    long long strideA, long long strideBt, int strideBias, long long strideC,
    int do_relu)
{
    // LDS: [kchunk 0..3][row 0..127][8 bf16]  -> each frag read is one ds_read_b128,
    // lanes 0..15 read consecutive 16B rows -> conflict-free.
    __shared__ __align__(16) unsigned short As[4][128][8];
    __shared__ __align__(16) unsigned short Bs[4][128][8];

    const int zb = blockIdx.z;
    const unsigned short* Ab  = Aall  + (size_t)zb * strideA;
    const unsigned short* Btb = Btall + (size_t)zb * strideBt;
    const float* bias = biasall + (size_t)zb * strideBias;
    unsigned short* Cb = Call + (size_t)zb * strideC;

    const int tid  = threadIdx.x;
    const int lane = tid & 63;
    const int wave = tid >> 6;     // 0..3
    const int wm = wave >> 1;      // 0..1
    const int wn = wave & 1;       // 0..1
    const int quad = lane >> 4;    // 0..3 -> k-chunk
    const int l16  = lane & 15;

    const int bm = blockIdx.x * 128;
    const int bn = blockIdx.y * 128;

    const int r0 = tid >> 2;       // 0..63
    const int c0 = tid & 3;        // k-chunk 0..3

    floatx4 acc[4][4];
#pragma unroll
    for (int i = 0; i < 4; i++)
#pragma unroll
        for (int j = 0; j < 4; j++)
            acc[i][j] = (floatx4){0.f, 0.f, 0.f, 0.f};

    const unsigned short* aptr0 = Ab  + (size_t)(bm + r0)      * Kd + c0 * 8;
    const unsigned short* aptr1 = Ab  + (size_t)(bm + 64 + r0) * Kd + c0 * 8;
    const unsigned short* bptr0 = Btb + (size_t)(bn + r0)      * Kd + c0 * 8;
    const unsigned short* bptr1 = Btb + (size_t)(bn + 64 + r0) * Kd + c0 * 8;

    for (int k0 = 0; k0 < Kd; k0 += 32) {
        uint4v a0 = *(const uint4v*)(aptr0 + k0);
        uint4v a1 = *(const uint4v*)(aptr1 + k0);
        uint4v b0 = *(const uint4v*)(bptr0 + k0);
        uint4v b1 = *(const uint4v*)(bptr1 + k0);
        __syncthreads();   // previous iter's frag reads done before overwrite
        *(uint4v*)&As[c0][r0][0]      = a0;
        *(uint4v*)&As[c0][64 + r0][0] = a1;
        *(uint4v*)&Bs[c0][r0][0]      = b0;
        *(uint4v*)&Bs[c0][64 + r0][0] = b1;
        __syncthreads();

        short8 af[4], bfr[4];
#pragma unroll
        for (int i = 0; i < 4; i++)
            af[i] = *(const short8*)&As[quad][wm * 64 + i * 16 + l16][0];
#pragma unroll
        for (int j = 0; j < 4; j++)
            bfr[j] = *(const short8*)&Bs[quad][wn * 64 + j * 16 + l16][0];
#pragma unroll
        for (int i = 0; i < 4; i++)
#pragma unroll
            for (int j = 0; j < 4; j++)
                acc[i][j] = __builtin_amdgcn_mfma_f32_16x16x32_bf16(
                    af[i], bfr[j], acc[i][j], 0, 0, 0);
    }

    // Epilogue. C/D layout (verified m89/m91): col = lane&15, row = quad*4 + reg.
#pragma unroll
    for (int j = 0; j < 4; j++) {
        int col = bn + wn * 64 + j * 16 + l16;
        float bv = bias[col];
#pragma unroll
        for (int i = 0; i < 4; i++) {
            int rowb = bm + wm * 64 + i * 16 + quad * 4;
#pragma unroll
            for (int r = 0; r < 4; r++) {
                float v = acc[i][j][r] + bv;
                if (do_relu) v = fmaxf(v, 0.f);
                Cb[(size_t)(rowb + r) * N + col] = f2bf(v);
            }
        }
    }
}

// ---------------- per-(k,b) row: lse over A and action logprob ----------------
__global__ __launch_bounds__(256) void row_reduce_kernel(
    const unsigned short* __restrict__ logits,  // [K][B][A] bf16
    const int* __restrict__ actions,            // [B]
    float* __restrict__ lse,                    // [K][B]
    float* __restrict__ alp)                    // [K][B]
{
    int row  = blockIdx.x * 4 + (threadIdx.x >> 6);   // k*NB + b
    int lane = threadIdx.x & 63;
    int b = row & (NB - 1);
    const unsigned short* p = logits + (size_t)row * ACTN;
    ushort8 u0 = *(const ushort8*)(p + lane * 8);
    ushort8 u1 = *(const ushort8*)(p + 512 + lane * 8);
    float v[16];
#pragma unroll
    for (int j = 0; j < 8; j++) { v[j] = bf2f(u0[j]); v[8 + j] = bf2f(u1[j]); }
    float m = v[0];
#pragma unroll
    for (int j = 1; j < 16; j++) m = fmaxf(m, v[j]);
#pragma unroll
    for (int off = 32; off > 0; off >>= 1) m = fmaxf(m, __shfl_xor(m, off));
    float s = 0.f;
#pragma unroll
    for (int j = 0; j < 16; j++) s += __expf(v[j] - m);
#pragma unroll
    for (int off = 32; off > 0; off >>= 1) s += __shfl_xor(s, off);
    float l = m + __logf(s);

    int act = actions[b];
    int chunk = act >> 9;        // 0/1 : which 512-wide half
    int within = act & 511;
    float av = 0.f;
    if (lane == (within >> 3)) av = v[chunk * 8 + (within & 7)];
#pragma unroll
    for (int off = 32; off > 0; off >>= 1) av += __shfl_xor(av, off);

    if (lane == 0) { lse[row] = l; alp[row] = av - l; }
}

// ---------------- per-sequence scan + mixture posterior ----------------
__global__ __launch_bounds__(128) void mix_kernel(
    const float* __restrict__ alp,    // [K][B]
    const float* __restrict__ start,  // [S][K]
    const float* __restrict__ lse,    // [K][B]
    float* __restrict__ w,            // [K][B]  = mix - lse
    float* __restrict__ fmix)         // [S][K]  final_mixture_logprobs
{
    __shared__ float buf[2][NT][9];
    int s = blockIdx.x, t = threadIdx.x;
    int b = s * NT + t;
    float a[KC];
#pragma unroll
    for (int k = 0; k < KC; k++) a[k] = alp[(size_t)k * NB + b];
#pragma unroll
    for (int k = 0; k < KC; k++) buf[0][t][k] = a[k];
    int p = 0;
    for (int off = 1; off < NT; off <<= 1) {
        __syncthreads();
#pragma unroll
        for (int k = 0; k < KC; k++) {
            float x = buf[p][t][k];
            if (t >= off) x += buf[p][t - off][k];
            buf[1 - p][t][k] = x;
        }
        p ^= 1;
    }
    __syncthreads();
    float st[KC], e[KC];
#pragma unroll
    for (int k = 0; k < KC; k++) st[k] = start[s * KC + k];
    // exclusive cumsum = inclusive - own
#pragma unroll
    for (int k = 0; k < KC; k++) e[k] = st[k] + buf[p][t][k] - a[k];
    float m = e[0];
#pragma unroll
    for (int k = 1; k < KC; k++) m = fmaxf(m, e[k]);
    float sum = 0.f;
#pragma unroll
    for (int k = 0; k < KC; k++) sum += __expf(e[k] - m);
    float l = m + __logf(sum);
#pragma unroll
    for (int k = 0; k < KC; k++)
        w[(size_t)k * NB + b] = (e[k] - l) - lse[(size_t)k * NB + b];

    if (t == NT - 1) {
        float f[KC];
#pragma unroll
        for (int k = 0; k < KC; k++) f[k] = st[k] + buf[p][t][k];  // inclusive full sum
        float m2 = f[0];
#pragma unroll
        for (int k = 1; k < KC; k++) m2 = fmaxf(m2, f[k]);
        float s2 = 0.f;
#pragma unroll
        for (int k = 0; k < KC; k++) s2 += __expf(f[k] - m2);
        float l2 = m2 + __logf(s2);
#pragma unroll
        for (int k = 0; k < KC; k++) fmix[s * KC + k] = f[k] - l2;
    }
}

// ---------------- final combine: out[b,a] = LSE_k(logits[k,b,a] + w[k,b]) ----------------
__global__ __launch_bounds__(128) void combine_kernel(
    const unsigned short* __restrict__ logits,  // [K][B][A] bf16
    const float* __restrict__ w,                // [K][B]
    float* __restrict__ out)                    // [B][A]
{
    int b = blockIdx.x;
    int a0 = threadIdx.x * 8;
    float wv[KC];
#pragma unroll
    for (int k = 0; k < KC; k++) wv[k] = w[(size_t)k * NB + b];
    float x[KC][8];
#pragma unroll
    for (int k = 0; k < KC; k++) {
        ushort8 u = *(const ushort8*)(logits + ((size_t)k * NB + b) * ACTN + a0);
#pragma unroll
        for (int j = 0; j < 8; j++) x[k][j] = bf2f(u[j]) + wv[k];
    }
    float* op = out + (size_t)b * ACTN + a0;
#pragma unroll
    for (int j = 0; j < 8; j++) {
        float m = x[0][j];
#pragma unroll
        for (int k = 1; k < KC; k++) m = fmaxf(m, x[k][j]);
        float s = 0.f;
#pragma unroll
        for (int k = 0; k < KC; k++) s += __expf(x[k][j] - m);
        op[j] = m + __logf(s);
    }
}

extern "C" void kernel_launch(void* const* d_in, const int* in_sizes, int n_in,
                              void* d_out, int out_size, void* d_ws, size_t ws_size,
                              hipStream_t stream)
{
    const float* obs     = (const float*)d_in[0];
    const int*   actions = (const int*)d_in[1];
    const float* start   = (const float*)d_in[2];
    const float* W1      = (const float*)d_in[3];
    const float* b1      = (const float*)d_in[4];
    const float* W2      = (const float*)d_in[5];
    const float* b2      = (const float*)d_in[6];
    // d_in[7] = seq_len (compile-time NT)

    char* ws = (char*)d_ws;
    unsigned short* obs_bf = (unsigned short*)ws; ws += (size_t)NB * DIM * 2;        // 8 MB
    unsigned short* W1t    = (unsigned short*)ws; ws += (size_t)KC * HID * DIM * 2;  // 4 MB
    unsigned short* W2t    = (unsigned short*)ws; ws += (size_t)KC * ACTN * HID * 2; // 8 MB
    unsigned short* hbuf   = (unsigned short*)ws; ws += (size_t)KC * NB * HID * 2;   // 64 MB
    unsigned short* logits = (unsigned short*)ws; ws += (size_t)KC * NB * ACTN * 2;  // 128 MB
    float* lse  = (float*)ws; ws += (size_t)KC * NB * 4;                             // 256 KB
    float* alp  = (float*)ws; ws += (size_t)KC * NB * 4;                             // 256 KB
    float* wbuf = (float*)ws; ws += (size_t)KC * NB * 4;                             // 256 KB

    float* out  = (float*)d_out;
    float* fmix = out + (size_t)NB * ACTN;

    // 1. dtype conversion / weight transposes
    convert_bf16_kernel<<<(NB * DIM / 8 + 255) / 256, 256, 0, stream>>>(obs, obs_bf, NB * DIM / 8);
    transpose_bf16_kernel<<<dim3(HID / 32, DIM / 32, KC), dim3(32, 8), 0, stream>>>(W1, W1t, DIM, HID);
    transpose_bf16_kernel<<<dim3(ACTN / 32, HID / 32, KC), dim3(32, 8), 0, stream>>>(W2, W2t, HID, ACTN);

    // 2. h = relu(obs @ W1[k] + b1[k])  -> bf16 [K][B][H]
    gemm_bt_kernel<<<dim3(NB / 128, HID / 128, KC), 256, 0, stream>>>(
        obs_bf, W1t, b1, hbuf, NB, HID, DIM,
        0LL, (long long)HID * DIM, HID, (long long)NB * HID, 1);

    // 3. logits = h @ W2[k] + b2[k]  -> bf16 [K][B][A]
    gemm_bt_kernel<<<dim3(NB / 128, ACTN / 128, KC), 256, 0, stream>>>(
        hbuf, W2t, b2, logits, NB, ACTN, HID,
        (long long)NB * HID, (long long)ACTN * HID, ACTN, (long long)NB * ACTN, 0);

    // 4. per-(k,b): lse over actions + taken-action logprob
    row_reduce_kernel<<<KC * NB / 4, 256, 0, stream>>>(logits, actions, lse, alp);

    // 5. per-sequence cumsum -> posterior mixture weights + final mixture logprobs
    mix_kernel<<<NS, NT, 0, stream>>>(alp, start, lse, wbuf, fmix);

    // 6. combine over components
    combine_kernel<<<NB, ACTN / 8, 0, stream>>>(logits, wbuf, out);
}